// Round 5
// baseline (549.698 us; speedup 1.0000x reference)
//
#include <hip/hip_runtime.h>
#include <math.h>

#define NF        128
#define H_DIM     256
#define NA        200
#define B_SAMPLES 512
#define ALPHA_LR  0.01f
#define B_MIN_C   1e-4f

#define NTHREADS  512
#define ROWS_PER_WAVE 25            // exact-path: 8 waves x 25 rows
#define SLAB_STRIDE 27              // odd -> 2-way bank aliasing (free)
#define CHUNK_ROWS 64
#define CB_STRIDE  51               // chunkbuf row stride (odd)

#define N_PH1     10
#define N_REFINE  2
#define CG_MAX    40
#define TOL2_LO   4e-4f
#define TOL2_HI   2.5e-2f

// ---------------- DPP wave-64 reductions (result valid in lane 63) --------
__device__ __forceinline__ float dpp_wave_sum(float v){
  v += __int_as_float(__builtin_amdgcn_update_dpp(0, __float_as_int(v), 0x111, 0xf, 0xf, false));
  v += __int_as_float(__builtin_amdgcn_update_dpp(0, __float_as_int(v), 0x112, 0xf, 0xf, false));
  v += __int_as_float(__builtin_amdgcn_update_dpp(0, __float_as_int(v), 0x114, 0xf, 0xf, false));
  v += __int_as_float(__builtin_amdgcn_update_dpp(0, __float_as_int(v), 0x118, 0xf, 0xf, false));
  v += __int_as_float(__builtin_amdgcn_update_dpp(0, __float_as_int(v), 0x142, 0xa, 0xf, false));
  v += __int_as_float(__builtin_amdgcn_update_dpp(0, __float_as_int(v), 0x143, 0xc, 0xf, false));
  return v;
}
__device__ __forceinline__ float dpp_wave_min(float v){
  const int PINF = 0x7f800000;
  v = fminf(v, __int_as_float(__builtin_amdgcn_update_dpp(PINF, __float_as_int(v), 0x111, 0xf, 0xf, false)));
  v = fminf(v, __int_as_float(__builtin_amdgcn_update_dpp(PINF, __float_as_int(v), 0x112, 0xf, 0xf, false)));
  v = fminf(v, __int_as_float(__builtin_amdgcn_update_dpp(PINF, __float_as_int(v), 0x114, 0xf, 0xf, false)));
  v = fminf(v, __int_as_float(__builtin_amdgcn_update_dpp(PINF, __float_as_int(v), 0x118, 0xf, 0xf, false)));
  v = fminf(v, __int_as_float(__builtin_amdgcn_update_dpp(PINF, __float_as_int(v), 0x142, 0xa, 0xf, false)));
  v = fminf(v, __int_as_float(__builtin_amdgcn_update_dpp(PINF, __float_as_int(v), 0x143, 0xc, 0xf, false)));
  return v;
}
__device__ __forceinline__ float dpp_wave_max(float v){
  const int NINF = 0xff800000;
  v = fmaxf(v, __int_as_float(__builtin_amdgcn_update_dpp(NINF, __float_as_int(v), 0x111, 0xf, 0xf, false)));
  v = fmaxf(v, __int_as_float(__builtin_amdgcn_update_dpp(NINF, __float_as_int(v), 0x112, 0xf, 0xf, false)));
  v = fmaxf(v, __int_as_float(__builtin_amdgcn_update_dpp(NINF, __float_as_int(v), 0x114, 0xf, 0xf, false)));
  v = fmaxf(v, __int_as_float(__builtin_amdgcn_update_dpp(NINF, __float_as_int(v), 0x118, 0xf, 0xf, false)));
  v = fmaxf(v, __int_as_float(__builtin_amdgcn_update_dpp(NINF, __float_as_int(v), 0x142, 0xa, 0xf, false)));
  v = fmaxf(v, __int_as_float(__builtin_amdgcn_update_dpp(NINF, __float_as_int(v), 0x143, 0xc, 0xf, false)));
  return v;
}
// block reductions (prologue only)
__device__ __forceinline__ float block_sum8(float v, float* red8, int tid){
  __syncthreads();
  v = dpp_wave_sum(v);
  if ((tid & 63) == 63) red8[tid >> 6] = v;
  __syncthreads();
  float o = red8[0];
  #pragma unroll
  for (int w = 1; w < 8; ++w) o += red8[w];
  return o;
}
__device__ __forceinline__ float block_max8(float v, float* red8, int tid){
  __syncthreads();
  v = dpp_wave_max(v);
  if ((tid & 63) == 63) red8[tid >> 6] = v;
  __syncthreads();
  float o = red8[0];
  #pragma unroll
  for (int w = 1; w < 8; ++w) o = fmaxf(o, red8[w]);
  return o;
}

// hybrid half-row matvec: 25 packed dwords from VGPRs + 25 from LDS slab
__device__ __forceinline__ float mv_hybrid(const unsigned* mreg,
                                           const unsigned* __restrict__ slab,
                                           const float* __restrict__ vv,
                                           int tid, int half){
  const float2* v2 = (const float2*)vv + half * 50;
  const unsigned* sl = slab + tid * SLAB_STRIDE;
  float a0=0.f, a1=0.f, a2=0.f, a3=0.f;
  #pragma unroll
  for (int k = 0; k < 25; ++k){
    unsigned u = mreg[k]; float2 x = v2[k];
    a0 = fmaf(__uint_as_float(u << 16),          x.x, a0);
    a1 = fmaf(__uint_as_float(u & 0xffff0000u),  x.y, a1);
  }
  #pragma unroll
  for (int k = 0; k < 25; ++k){
    unsigned u = sl[k]; float2 x = v2[25 + k];
    a2 = fmaf(__uint_as_float(u << 16),          x.x, a2);
    a3 = fmaf(__uint_as_float(u & 0xffff0000u),  x.y, a3);
  }
  return (a0 + a1) + (a2 + a3);
}

extern "C" __global__ __launch_bounds__(NTHREADS)
void rb_kernel(const float* __restrict__ x,  const float* __restrict__ Sigma,
               const float* __restrict__ W1, const float* __restrict__ b1,
               const float* __restrict__ W2, const float* __restrict__ b2,
               float* __restrict__ out) {
  __shared__ __align__(16) unsigned slab[400 * SLAB_STRIDE];     // 43.2 KB
  __shared__ __align__(16) unsigned chunkbuf[CHUNK_ROWS * CB_STRIDE]; // 13.1 KB
  __shared__ __align__(16) float yv[NA];
  __shared__ __align__(16) float pv[NA];
  __shared__ __align__(16) float partial[NA];
  __shared__ __align__(16) float bcv[NA];
  __shared__ float xs[NF];
  __shared__ float hs[H_DIM];
  __shared__ float redA[8], redB[8], redC[8], redD[8], red8[8];

  const int tid  = threadIdx.x;
  const int s    = blockIdx.x;
  const bool act = tid < 400;
  const int row  = tid >> 1;              // valid when act
  const int half = tid & 1;
  const bool owner = act && (half == 0);
  const float* S = Sigma + (size_t)s * NA * NA;

  if (tid < NF) xs[tid] = x[s * NF + tid];
  float sd = 0.f;
  if (owner) sd = S[(size_t)row * NA + row];

  // ---- stage Sigma: bf16-pack; 25 dwords/thread -> VGPRs, 25 -> LDS slab ----
  unsigned mreg[25];
  const float2* Sg2 = (const float2*)S;   // row pitch = 100 float2
  for (int c = 0; c < 4; ++c){
    const int c0 = c * CHUNK_ROWS;
    const int nr = (c == 3) ? (NA - 3 * CHUNK_ROWS) : CHUNK_ROWS;  // 64,64,64,8
    for (int i = tid; i < nr * 100; i += NTHREADS){
      int rl = i / 100, p = i - rl * 100;
      float2 w = Sg2[(size_t)c0 * 100 + i];
      unsigned bx = __float_as_uint(w.x); bx = (bx + 0x7fffu + ((bx >> 16) & 1u)) >> 16;
      unsigned by = __float_as_uint(w.y); by = (by + 0x7fffu + ((by >> 16) & 1u)) >> 16;
      unsigned u = bx | (by << 16);
      int h = p / 50, kk = p - h * 50;
      if (kk < 25) chunkbuf[rl * CB_STRIDE + h * 25 + kk] = u;
      else         slab[((c0 + rl) * 2 + h) * SLAB_STRIDE + (kk - 25)] = u;
    }
    __syncthreads();
    if (act && row >= c0 && row < c0 + nr){
      const unsigned* src = chunkbuf + (row - c0) * CB_STRIDE + half * 25;
      #pragma unroll
      for (int k = 0; k < 25; ++k) mreg[k] = src[k];
    }
    __syncthreads();
  }

  // ---- MLP ----
  if (tid < H_DIM){
    const float* w = W1 + tid * NF;
    float acc = b1[tid];
    #pragma unroll 8
    for (int j = 0; j < NF; ++j) acc += w[j] * xs[j];
    hs[tid] = (acc >= 0.f) ? acc : ALPHA_LR * acc;
  }
  __syncthreads();
  float logit = -INFINITY;
  if (tid < NA){
    const float* w = W2 + tid * H_DIM;
    float acc = b2[tid];
    #pragma unroll 8
    for (int j = 0; j < H_DIM; ++j) acc += w[j] * hs[j];
    logit = acc;
  }

  // ---- softmax -> b (output 2); clamp+renorm -> bcv ----
  float mx = block_max8(logit, red8, tid);
  float e  = (tid < NA) ? expf(logit - mx) : 0.f;
  float es = block_sum8(e, red8, tid);
  float bsoft = e / es;
  if (tid < NA) out[(size_t)B_SAMPLES * NA + (size_t)s * NA + tid] = bsoft;
  float bcl = fmaxf(bsoft, B_MIN_C);
  float bs  = block_sum8((tid < NA) ? bcl : 0.f, red8, tid);
  if (tid < NA) bcv[tid] = bcl / bs;
  __syncthreads();                               // bcv visible to owners

  float b_ = owner ? bcv[row] : 0.f;
  float y  = 0.f;
  if (owner) yv[row] = b_;

  // ---- y0 = bc / sqrt(bc^T S bc) ----
  __syncthreads();                               // yv visible
  {
    float acc = act ? mv_hybrid(mreg, slab, yv, tid, half) : 0.f;
    float q   = acc + __shfl_xor(acc, 1, 64);
    float wq  = dpp_wave_sum(owner ? b_ * q : 0.f);
    if ((tid & 63) == 63) redA[tid >> 6] = wq;
    __syncthreads();
    float quad = redA[0]+redA[1]+redA[2]+redA[3]+redA[4]+redA[5]+redA[6]+redA[7];
    if (owner){ y = b_ / sqrtf(quad); yv[row] = y; }
  }

  // ---- damped inexact Newton ----
  float gg0 = 1.f;
  bool  ph1done = false;
  int   nexact  = 0;
  for (int it = 0; it < N_PH1 + N_REFINE; ++it){
    if (nexact >= N_REFINE) break;
    const bool exact = ph1done;
    if (exact) ++nexact;

    // --- gradient matvec q = (S y)_row ---
    float q = 0.f;
    if (exact){
      __syncthreads();                           // yv visible, partial free
      int lane = tid & 63, wid = tid >> 6;
      int r0 = wid * ROWS_PER_WAVE;
      for (int rr = r0; rr < r0 + ROWS_PER_WAVE; ++rr){
        const float* rowp = S + (size_t)rr * NA;
        float a = rowp[lane]*yv[lane] + rowp[lane+64]*yv[lane+64]
                + rowp[lane+128]*yv[lane+128];
        if (lane < NA - 192) a += rowp[lane+192]*yv[lane+192];
        a = dpp_wave_sum(a);
        if (lane == 63) partial[rr] = a;
      }
      __syncthreads();
      if (owner) q = partial[row];
    } else {
      __syncthreads();                           // yv visible
      float acc = act ? mv_hybrid(mreg, slab, yv, tid, half) : 0.f;
      q = acc + __shfl_xor(acc, 1, 64);
    }

    // --- Newton init ---
    float g=0.f, d=0.f, mi=0.f, r=0.f, z=0.f, dy=0.f, pj=0.f;
    if (owner){
      g  = q - b_ / y;
      d  = b_ / (y * y);
      mi = 1.f / (sd + d);
      r  = -g; z = mi * r; pj = z;
      pv[row] = z;
    }
    float wg = dpp_wave_sum(owner ? g * g : 0.f);
    float wz = dpp_wave_sum(owner ? r * z : 0.f);
    if ((tid & 63) == 63){ redA[tid >> 6] = wg; redB[tid >> 6] = wz; }
    __syncthreads();
    float gg = redA[0]+redA[1]+redA[2]+redA[3]+redA[4]+redA[5]+redA[6]+redA[7];
    float rz = redB[0]+redB[1]+redB[2]+redB[3]+redB[4]+redB[5]+redB[6]+redB[7];
    if (it == 0) gg0 = fmaxf(gg, 1e-30f);
    float tol2 = exact ? TOL2_LO
                       : fminf(TOL2_HI, fmaxf(TOL2_LO, 4.f * (gg / gg0)));

    if (gg > 1e-24f){
      // --- Jacobi-PCG, fused single reduction (pq, rq, qq) ---
      const float rz0 = rz;
      for (int j = 0; j < CG_MAX; ++j){
        __syncthreads();                         // B1: pv visible, red reuse safe
        float acc = act ? mv_hybrid(mreg, slab, pv, tid, half) : 0.f;
        float qp  = acc + __shfl_xor(acc, 1, 64);
        float qf=0.f, cpq=0.f, crq=0.f, cqq=0.f;
        if (owner){
          qf = qp + d * pj;
          float u = mi * qf;
          cpq = pj * qf; crq = r * u; cqq = qf * u;
        }
        cpq = dpp_wave_sum(cpq); crq = dpp_wave_sum(crq); cqq = dpp_wave_sum(cqq);
        if ((tid & 63) == 63){ redA[tid>>6]=cpq; redB[tid>>6]=crq; redC[tid>>6]=cqq; }
        __syncthreads();                         // B2
        float pq = redA[0]+redA[1]+redA[2]+redA[3]+redA[4]+redA[5]+redA[6]+redA[7];
        float rq = redB[0]+redB[1]+redB[2]+redB[3]+redB[4]+redB[5]+redB[6]+redB[7];
        float qq = redC[0]+redC[1]+redC[2]+redC[3]+redC[4]+redC[5]+redC[6]+redC[7];
        float alpha = rz / pq;
        float rznew = fmaxf(fmaf(alpha*alpha, qq, fmaf(-2.f*alpha, rq, rz)), 0.f);
        if (owner){
          dy = fmaf(alpha, pj, dy);
          r  = fmaf(-alpha, qf, r);
          z  = mi * r;
        }
        bool brk = (rznew <= tol2 * rz0) || (j == CG_MAX - 1);
        if (!brk){
          float beta = rznew / rz;
          if (owner){ pj = fmaf(beta, pj, z); pv[row] = pj; }
        }
        rz = rznew;
        if (brk) break;
      }

      // --- damped step keeping y > 0 (reference semantics) ---
      float ratio = (owner && dy < 0.f) ? (-y / dy) : 1e30f;
      float wmn = dpp_wave_min(ratio);
      if ((tid & 63) == 63) redD[tid >> 6] = wmn;
      __syncthreads();
      float mr = fminf(fminf(fminf(redD[0],redD[1]),fminf(redD[2],redD[3])),
                       fminf(fminf(redD[4],redD[5]),fminf(redD[6],redD[7])));
      float t = fminf(1.f, 0.9f * mr);
      if (owner){ y = fmaxf(fmaf(t, dy, y), 1e-12f); yv[row] = y; }
    }

    if (!exact && (gg <= 1e-8f * gg0 || it + 1 >= N_PH1)) ph1done = true;
  }

  // ---- z = y / sum(y) (output 1) ----
  float wy = dpp_wave_sum(owner ? y : 0.f);
  if ((tid & 63) == 63) redA[tid >> 6] = wy;   // safe: >=1 barrier since last redA read
  __syncthreads();
  float ys = redA[0]+redA[1]+redA[2]+redA[3]+redA[4]+redA[5]+redA[6]+redA[7];
  if (owner) out[(size_t)s * NA + row] = y / ys;
}

extern "C" void kernel_launch(void* const* d_in, const int* in_sizes, int n_in,
                              void* d_out, int out_size, void* d_ws, size_t ws_size,
                              hipStream_t stream) {
  const float* x     = (const float*)d_in[0];
  const float* Sigma = (const float*)d_in[1];
  const float* W1    = (const float*)d_in[2];
  const float* b1    = (const float*)d_in[3];
  const float* W2    = (const float*)d_in[4];
  const float* b2    = (const float*)d_in[5];
  float* out = (float*)d_out;
  hipLaunchKernelGGL(rb_kernel, dim3(B_SAMPLES), dim3(NTHREADS), 0, stream,
                     x, Sigma, W1, b1, W2, b2, out);
}